// Round 1
// baseline (1197.546 us; speedup 1.0000x reference)
//
#include <hip/hip_runtime.h>

// Problem constants
#define NV   20000
#define PP   5
#define TT   16
#define KK   3
#define INF  150
#define HH   64
#define OO   128
#define PT   80      // PP*TT
#define KTOT 5120    // PT*HH

// ---------------------------------------------------------------------------
// Kernel C: rearrange Wg [O][H][P][T] -> Wgr [O][bin][h]  (bin = p*16+t)
// Wg offset (o,h,p,t) = o*5120 + h*80 + bin ; Wgr offset = o*5120 + bin*64 + h
// ---------------------------------------------------------------------------
__global__ void wgr_kernel(const float* __restrict__ Wg, float* __restrict__ Wgr) {
    int e = blockIdx.x * 256 + threadIdx.x;
    if (e >= OO * KTOT) return;
    int o   = e / KTOT;
    int rem = e - o * KTOT;
    int bin = rem >> 6;
    int hh  = rem & 63;
    Wgr[e] = Wg[o * KTOT + hh * PT + bin];
}

// ---------------------------------------------------------------------------
// Kernel A: h = relu(x @ W1^T)   x:[N,150] W1:[64,150] -> h:[N,64]
// block: 256 threads = 64 c  x 4 groups; each thread computes 4 rows.
// 16 rows per block -> grid 1250.
// ---------------------------------------------------------------------------
__global__ __launch_bounds__(256, 2) void linear_relu_kernel(
    const float* __restrict__ x, const float* __restrict__ W1,
    float* __restrict__ h) {
    __shared__ float w1s[64 * 156];   // stride 156: 16B aligned, pad breaks conflicts
    __shared__ float xs[16 * 152];
    const int tid = threadIdx.x;
    const int n0  = blockIdx.x * 16;

    for (int e = tid; e < 64 * INF; e += 256) {
        int c = e / INF;
        int i = e - c * INF;
        w1s[c * 156 + i] = W1[e];
    }
    if (tid < 64) { w1s[tid * 156 + 150] = 0.f; w1s[tid * 156 + 151] = 0.f; }
    for (int e = tid; e < 16 * INF; e += 256) {
        int r = e / INF;
        int i = e - r * INF;
        xs[r * 152 + i] = x[n0 * INF + e];
    }
    if (tid < 16) { xs[tid * 152 + 150] = 0.f; xs[tid * 152 + 151] = 0.f; }
    __syncthreads();

    const int c  = tid & 63;
    const int r0 = (tid >> 6) * 4;
    float acc[4] = {0.f, 0.f, 0.f, 0.f};
    for (int ii = 0; ii < 38; ii++) {   // 38*4 = 152 (zero-padded)
        float4 wv = *(const float4*)&w1s[c * 156 + ii * 4];
        #pragma unroll
        for (int q = 0; q < 4; q++) {
            float4 xv = *(const float4*)&xs[(r0 + q) * 152 + ii * 4];
            acc[q] += wv.x * xv.x + wv.y * xv.y + wv.z * xv.z + wv.w * xv.w;
        }
    }
    #pragma unroll
    for (int q = 0; q < 4; q++) {
        float v = acc[q] > 0.f ? acc[q] : 0.f;
        h[(n0 + r0 + q) * HH + c] = v;
    }
}

// ---------------------------------------------------------------------------
// Kernel B: fused gather + geodesic conv + bias + L2 normalize
// BN=16 vertices/block, 10 chunks of 8 bins.
// Phase1: patches chunk -> LDS pch[16][8*64] (stride 516, padded)
// Phase2: register tile 8 o x 8 n per thread; 32 tile positions x 8 j-splits.
// ---------------------------------------------------------------------------
__global__ __launch_bounds__(256, 2) void geo_conv_kernel(
    const int*   __restrict__ conn_idx, const float* __restrict__ conn_w,
    const float* __restrict__ Wgr,      const float* __restrict__ h,
    const float* __restrict__ bg,       float* __restrict__ out) {
    __shared__ float pch[16 * 516];     // 16 rows x (512 used + 4 pad)
    __shared__ float outbuf[16 * 128];
    __shared__ int   wi[384];           // 16 nl x 8 bins x 3 k
    __shared__ float ww[384];
    __shared__ float rowsum[16];

    const int tid = threadIdx.x;
    const int n0  = blockIdx.x * 16;

    const int p      = tid & 31;
    const int jsplit = tid >> 5;          // 0..7
    const int o0     = (p & 15) * 8;      // 16 o-groups
    const int nl0    = (p >> 4) * 8;      // 2 n-groups

    float acc[8][8];
    #pragma unroll
    for (int a = 0; a < 8; a++)
        #pragma unroll
        for (int b = 0; b < 8; b++) acc[a][b] = 0.f;

    for (int cc = 0; cc < 10; cc++) {
        const int c0 = cc * 8;
        __syncthreads();   // previous phase2 done reading pch
        // stage connectivity for this chunk: [16][8][3]
        for (int e = tid; e < 384; e += 256) {
            int nl  = e / 24;
            int rem = e - nl * 24;            // bin_local*3 + k
            int g   = (n0 + nl) * (PT * KK) + c0 * KK + rem;
            wi[e] = conn_idx[g];
            ww[e] = conn_w[g];
        }
        __syncthreads();
        // gather: pch[nl][b*64+h4..] = sum_k w * h[idx][h4..]
        #pragma unroll
        for (int i = 0; i < 8; i++) {
            int e  = tid + (i << 8);          // 0..2047 float4 elems
            int h4 = (e & 15) << 2;
            int nb = e >> 4;                  // 0..127
            int nl = nb >> 3;
            int b  = nb & 7;
            int base = nl * 24 + b * 3;
            float4 v = make_float4(0.f, 0.f, 0.f, 0.f);
            #pragma unroll
            for (int k = 0; k < 3; k++) {
                float  wk = ww[base + k];
                float4 hv = *(const float4*)&h[wi[base + k] * HH + h4];
                v.x += wk * hv.x; v.y += wk * hv.y;
                v.z += wk * hv.z; v.w += wk * hv.w;
            }
            *(float4*)&pch[nl * 516 + b * 64 + h4] = v;
        }
        __syncthreads();
        // contraction: acc[nn][oo] += pch[nl0+nn][j..] . Wgr[o0+oo][chunk j..]
        const int wbase = cc * 512;
        for (int jj = 0; jj < 16; jj++) {
            int j = jsplit * 64 + jj * 4;
            float4 wg[8];
            #pragma unroll
            for (int oo = 0; oo < 8; oo++)
                wg[oo] = *(const float4*)&Wgr[(o0 + oo) * KTOT + wbase + j];
            float4 pv[8];
            #pragma unroll
            for (int nn = 0; nn < 8; nn++)
                pv[nn] = *(const float4*)&pch[(nl0 + nn) * 516 + j];
            #pragma unroll
            for (int nn = 0; nn < 8; nn++)
                #pragma unroll
                for (int oo = 0; oo < 8; oo++)
                    acc[nn][oo] += pv[nn].x * wg[oo].x + pv[nn].y * wg[oo].y +
                                   pv[nn].z * wg[oo].z + pv[nn].w * wg[oo].w;
        }
    }

    // reduce partial sums across the 8 j-splits (rotated to avoid collisions)
    for (int e = tid; e < 2048; e += 256) outbuf[e] = 0.f;
    __syncthreads();
    #pragma unroll
    for (int nn = 0; nn < 8; nn++) {
        #pragma unroll
        for (int s = 0; s < 8; s++) {
            int oo = (jsplit + s) & 7;
            atomicAdd(&outbuf[(nl0 + nn) * 128 + o0 + oo], acc[nn][oo]);
        }
    }
    __syncthreads();

    // bias + row L2 norm (norm over out+bias, per reference)
    {
        int r = tid >> 4;
        int l = tid & 15;
        float s = 0.f;
        for (int o = l; o < 128; o += 16) {
            float v = outbuf[r * 128 + o] + bg[o];
            s += v * v;
        }
        for (int off = 8; off; off >>= 1) s += __shfl_down(s, off, 16);
        if (l == 0) rowsum[r] = rsqrtf(s);
    }
    __syncthreads();
    #pragma unroll
    for (int i = 0; i < 8; i++) {
        int e = tid + (i << 8);
        int r = e >> 7;
        int o = e & 127;
        out[(n0 + r) * 128 + o] = (outbuf[r * 128 + o] + bg[o]) * rowsum[r];
    }
}

// ---------------------------------------------------------------------------
extern "C" void kernel_launch(void* const* d_in, const int* in_sizes, int n_in,
                              void* d_out, int out_size, void* d_ws, size_t ws_size,
                              hipStream_t stream) {
    const float* x        = (const float*)d_in[0];
    const int*   conn_idx = (const int*)  d_in[1];
    const float* conn_w   = (const float*)d_in[2];
    const float* W1       = (const float*)d_in[3];
    const float* Wg       = (const float*)d_in[4];
    const float* bg       = (const float*)d_in[5];
    float*       out      = (float*)d_out;

    float* Wgr = (float*)d_ws;                    // 655360 floats (2.62 MB)
    float* h   = (float*)d_ws + OO * KTOT;        // 1,280,000 floats (5.12 MB)

    hipLaunchKernelGGL(wgr_kernel, dim3((OO * KTOT + 255) / 256), dim3(256), 0, stream,
                       Wg, Wgr);
    hipLaunchKernelGGL(linear_relu_kernel, dim3(NV / 16), dim3(256), 0, stream,
                       x, W1, h);
    hipLaunchKernelGGL(geo_conv_kernel, dim3(NV / 16), dim3(256), 0, stream,
                       conn_idx, conn_w, Wgr, h, bg, out);
}

// Round 2
// 210.980 us; speedup vs baseline: 5.6761x; 5.6761x over previous
//
#include <hip/hip_runtime.h>

// Problem constants
#define NV   20000
#define KK   3
#define INF  150
#define HH   64
#define OO   128
#define PT   80
#define KTOT 5120     // 80 bins * 64 h
#define NB   32       // vertices per geo block
#define BS   72       // per-bin stride in pch (64 + 8 pad, keeps 16B align)
#define RS   584      // pch row stride = 8*BS + 8  (1168 B = 292 words, %32==4)

typedef __attribute__((ext_vector_type(8))) short          bhalf8;  // MFMA A/B frag (4 VGPRs)
typedef __attribute__((ext_vector_type(4))) float          f32x4;   // MFMA C/D frag
typedef __attribute__((ext_vector_type(8))) unsigned short u16x8;

__device__ __forceinline__ unsigned short f2bf(float f) {   // RNE fp32->bf16
    unsigned int u = __float_as_uint(f);
    u += 0x7fffu + ((u >> 16) & 1u);
    return (unsigned short)(u >> 16);
}
__device__ __forceinline__ float bf2f(unsigned short s) {
    return __uint_as_float(((unsigned int)s) << 16);
}

// ---------------------------------------------------------------------------
// Repack Wg [O][H][P][T] fp32 -> W2 [S=k/32][o][kk] bf16, k = bin*64 + h.
// B-fragment for k-step S, o-tile ot is then ONE contiguous 1KB wave load.
// ---------------------------------------------------------------------------
__global__ void prep_w2_kernel(const float* __restrict__ Wg,
                               unsigned short* __restrict__ W2) {
    int e  = blockIdx.x * 256 + threadIdx.x;      // 655360 = 2560*256 exact
    int S  = e >> 12;
    int o  = (e >> 5) & 127;
    int kk = e & 31;
    int k  = S * 32 + kk;                         // k = bin*64 + h
    W2[e] = f2bf(Wg[o * KTOT + (k & 63) * PT + (k >> 6)]);
}

// ---------------------------------------------------------------------------
// h = relu(x @ W1^T) -> bf16 [N][64]
// ---------------------------------------------------------------------------
__global__ __launch_bounds__(256) void linear_relu_kernel(
    const float* __restrict__ x, const float* __restrict__ W1,
    unsigned short* __restrict__ hb) {
    __shared__ float w1s[64 * 156];
    __shared__ float xs[16 * 152];
    const int tid = threadIdx.x;
    const int n0  = blockIdx.x * 16;

    for (int e = tid; e < 64 * INF; e += 256) {
        int c = e / INF, i = e - c * INF;
        w1s[c * 156 + i] = W1[e];
    }
    if (tid < 64) { w1s[tid * 156 + 150] = 0.f; w1s[tid * 156 + 151] = 0.f; }
    for (int e = tid; e < 16 * INF; e += 256) {
        int r = e / INF, i = e - r * INF;
        xs[r * 152 + i] = x[n0 * INF + e];
    }
    if (tid < 16) { xs[tid * 152 + 150] = 0.f; xs[tid * 152 + 151] = 0.f; }
    __syncthreads();

    const int c  = tid & 63;
    const int r0 = (tid >> 6) * 4;
    float acc[4] = {0.f, 0.f, 0.f, 0.f};
    for (int ii = 0; ii < 38; ii++) {
        float4 wv = *(const float4*)&w1s[c * 156 + ii * 4];
        #pragma unroll
        for (int qq = 0; qq < 4; qq++) {
            float4 xv = *(const float4*)&xs[(r0 + qq) * 152 + ii * 4];
            acc[qq] += wv.x * xv.x + wv.y * xv.y + wv.z * xv.z + wv.w * xv.w;
        }
    }
    #pragma unroll
    for (int qq = 0; qq < 4; qq++) {
        float v = acc[qq] > 0.f ? acc[qq] : 0.f;
        hb[(n0 + r0 + qq) * HH + c] = f2bf(v);
    }
}

// ---------------------------------------------------------------------------
// Fused gather + bf16 MFMA contraction + bias + L2 normalize.
// Block: 256 thr = 4 waves, 32 vertices. K-loop: 10 chunks of 8 bins (512 k).
// Wave w owns o-tiles {2w, 2w+1} x m-tiles {0,1} -> 4 mfma_f32_16x16x32_bf16
// per k-step. A-frags from LDS pch, B-frags straight from L2-resident W2.
// ---------------------------------------------------------------------------
__global__ __launch_bounds__(256) void geo_kernel(
    const int*   __restrict__ conn_idx, const float* __restrict__ conn_w,
    const unsigned short* __restrict__ W2, const unsigned short* __restrict__ hb,
    const float* __restrict__ bg, float* __restrict__ out) {
    __shared__ unsigned short pch[NB * RS];   // 37376 B; reused as outbuf in epilogue
    __shared__ int   wi[768];                 // 256 (n,bin) pairs x 3
    __shared__ float ww[768];
    __shared__ float rsq[NB];
    float* outbuf = (float*)pch;              // 32*132*4 = 16896 B <= 37376 B

    const int tid  = threadIdx.x;
    const int n0   = blockIdx.x * NB;
    const int wv   = tid >> 6;
    const int lane = tid & 63;
    const int q    = lane >> 4;               // quad 0..3
    const int r16  = lane & 15;

    f32x4 acc00 = {0.f, 0.f, 0.f, 0.f};
    f32x4 acc01 = acc00, acc10 = acc00, acc11 = acc00;

    for (int cc = 0; cc < 10; cc++) {
        __syncthreads();                      // prev MFMA phase done with pch/wi
        // stage connectivity for this chunk: pair p = n*8 + b_local
        for (int e = tid; e < 768; e += 256) {
            int p = e / 3, k = e - p * 3;
            int g = (n0 + (p >> 3)) * (PT * KK) + (cc * 8 + (p & 7)) * KK + k;
            wi[e] = conn_idx[g];
            ww[e] = conn_w[g];
        }
        __syncthreads();
        // gather: grain = 8 bf16; lanes j8=0..7 cover one h-row contiguously
        #pragma unroll
        for (int i = 0; i < 8; i++) {
            int e  = i * 256 + tid;
            int n  = e >> 6, b = (e >> 3) & 7, j8 = e & 7;
            int pb = (e >> 3) * 3;
            int i0 = wi[pb], i1 = wi[pb + 1], i2 = wi[pb + 2];
            float w0 = ww[pb], w1 = ww[pb + 1], w2 = ww[pb + 2];
            u16x8 h0 = *(const u16x8*)(hb + i0 * HH + j8 * 8);
            u16x8 h1 = *(const u16x8*)(hb + i1 * HH + j8 * 8);
            u16x8 h2 = *(const u16x8*)(hb + i2 * HH + j8 * 8);
            u16x8 r;
            #pragma unroll
            for (int j = 0; j < 8; j++) {
                float v = w0 * bf2f(h0[j]) + w1 * bf2f(h1[j]) + w2 * bf2f(h2[j]);
                r[j] = f2bf(v);
            }
            *(u16x8*)(pch + n * RS + b * BS + j8 * 8) = r;
        }
        __syncthreads();
        // MFMA phase: 16 k-steps of 32 over this chunk
        #pragma unroll
        for (int s = 0; s < 16; s++) {
            const int S  = cc * 16 + s;
            const int b  = s >> 1, hf = s & 1;
            const int ao = b * BS + hf * 32 + q * 8;
            bhalf8 a0 = *(const bhalf8*)(pch + r16 * RS + ao);
            bhalf8 a1 = *(const bhalf8*)(pch + (16 + r16) * RS + ao);
            bhalf8 b0 = *(const bhalf8*)(W2 + S * 4096 + ((wv * 2 + 0) * 16 + r16) * 32 + q * 8);
            bhalf8 b1 = *(const bhalf8*)(W2 + S * 4096 + ((wv * 2 + 1) * 16 + r16) * 32 + q * 8);
            acc00 = __builtin_amdgcn_mfma_f32_16x16x32_bf16(a0, b0, acc00, 0, 0, 0);
            acc01 = __builtin_amdgcn_mfma_f32_16x16x32_bf16(a0, b1, acc01, 0, 0, 0);
            acc10 = __builtin_amdgcn_mfma_f32_16x16x32_bf16(a1, b0, acc10, 0, 0, 0);
            acc11 = __builtin_amdgcn_mfma_f32_16x16x32_bf16(a1, b1, acc11, 0, 0, 0);
        }
    }

    __syncthreads();                          // done with pch; alias as outbuf
    {   // D layout: row = q*4+reg (vertex within tile), col = r16 (o within tile)
        const int o0 = wv * 32;
        #pragma unroll
        for (int r = 0; r < 4; r++) {
            outbuf[(q * 4 + r) * 132 + o0 + r16]           = acc00[r];
            outbuf[(q * 4 + r) * 132 + o0 + 16 + r16]      = acc01[r];
            outbuf[(16 + q * 4 + r) * 132 + o0 + r16]      = acc10[r];
            outbuf[(16 + q * 4 + r) * 132 + o0 + 16 + r16] = acc11[r];
        }
    }
    __syncthreads();
    {   // bias + row L2 norm
        int rr = tid >> 3, l = tid & 7;
        float s = 0.f;
        for (int o = l; o < 128; o += 8) {
            float v = outbuf[rr * 132 + o] + bg[o];
            s += v * v;
        }
        for (int off = 4; off; off >>= 1) s += __shfl_down(s, off, 8);
        if (l == 0) rsq[rr] = rsqrtf(s);
    }
    __syncthreads();
    #pragma unroll
    for (int i = 0; i < 16; i++) {
        int e = i * 256 + tid;
        int n = e >> 7, o = e & 127;
        out[(n0 + n) * OO + o] = (outbuf[n * 132 + o] + bg[o]) * rsq[n];
    }
}

// ---------------------------------------------------------------------------
extern "C" void kernel_launch(void* const* d_in, const int* in_sizes, int n_in,
                              void* d_out, int out_size, void* d_ws, size_t ws_size,
                              hipStream_t stream) {
    const float* x        = (const float*)d_in[0];
    const int*   conn_idx = (const int*)  d_in[1];
    const float* conn_w   = (const float*)d_in[2];
    const float* W1       = (const float*)d_in[3];
    const float* Wg       = (const float*)d_in[4];
    const float* bg       = (const float*)d_in[5];
    float*       out      = (float*)d_out;

    unsigned short* W2 = (unsigned short*)d_ws;            // 655360 bf16 (1.31 MB)
    unsigned short* hb = W2 + OO * KTOT;                   // 1,280,000 bf16 (2.56 MB)

    hipLaunchKernelGGL(prep_w2_kernel, dim3(2560), dim3(256), 0, stream, Wg, W2);
    hipLaunchKernelGGL(linear_relu_kernel, dim3(NV / 16), dim3(256), 0, stream, x, W1, hb);
    hipLaunchKernelGGL(geo_kernel, dim3(NV / NB), dim3(256), 0, stream,
                       conn_idx, conn_w, W2, hb, bg, out);
}